// Round 16
// baseline (190.424 us; speedup 1.0000x reference)
//
#include <hip/hip_runtime.h>
#include <hip/hip_bf16.h>

#define B_    4
#define N_    16384
#define K_    16
#define CIN_  64
#define CF_   67          // 3 + 64 concat channels
#define COUT_ 128
#define AGGP_ 1088        // 16*68 padded flattening (c=67 slot zero per w-row)
#define P_    32          // points per block (2 passes of 16 through phases 1-2)
#define PH_   16          // points per pass
#define FSTR  64          // bf16 record stride in shorts (128 B, 2 aligned lines)
#define ASTR  1096        // agg/FT row stride in shorts (2192 B, 16B-aligned)
#define WTS   272         // s_WT point stride in shorts: [w][k] 16x16 + 16 pad
#define NEG_  0.1f

typedef __attribute__((ext_vector_type(8))) short short8;
typedef __attribute__((ext_vector_type(4))) float f32x4;
typedef __attribute__((ext_vector_type(4))) _Float16 half4;
typedef __attribute__((ext_vector_type(2))) unsigned int uint2_t;
typedef __attribute__((ext_vector_type(4))) unsigned int uint4_t;

__device__ __forceinline__ unsigned short f2b(float f) {
    __hip_bfloat16 h = __float2bfloat16(f);
    return *reinterpret_cast<unsigned short*>(&h);
}
__device__ __forceinline__ float leaky(float x) { return x >= 0.f ? x : NEG_ * x; }

// ---------------------------------------------------------------------------
// Kernel 1 (fused prep):
//  blocks [0,1024):      ft bf16 [B][N][64] records + xyz3 [B][N][4] fp32
//  blocks [1024,1152):   lin_w -> lwb bf16 [128][16*68], columns permuted
//  blocks [1152,5248):   dxyz fp16 [B][N][K][4] = xyz[j]-xyz[n] precompute
//                        (reads RAW xyz — independent of xyz3/ft blocks; the
//                        scattered j-reads hit L2 at full occupancy since
//                        xyz = 786 KB).  This removes pc_main's only
//                        remaining removable scatter (x3[ja/jb], 128
//                        lines/wave) and un-chains the MLP from knn->x3.
// ---------------------------------------------------------------------------
__global__ __launch_bounds__(256) void pc_prep(
    const float* __restrict__ xyz,
    const float* __restrict__ feats,
    const float* __restrict__ lin_w,
    const int*   __restrict__ knn,
    unsigned short* __restrict__ ft,
    short* __restrict__ lwb,
    float* __restrict__ xyz3,
    _Float16* __restrict__ dxyz)
{
    const int bid = blockIdx.x, t = threadIdx.x;
    if (bid < 1024) {
        __shared__ float st[64][69];           // [j_local][c], +1 pad
        const int b  = bid >> 8;
        const int j0 = (bid & 255) << 6;
        for (int ii = t; ii < 68 * 16; ii += 256) {
            const int c = ii >> 4, jq = ii & 15;
            f32x4 v = {0.f, 0.f, 0.f, 0.f};
            if (c < 3)
                v = *(const f32x4*)(xyz   + ((size_t)b * 3    + c)       * N_ + j0 + 4 * jq);
            else if (c < CF_)
                v = *(const f32x4*)(feats + ((size_t)b * CIN_ + (c - 3)) * N_ + j0 + 4 * jq);
            st[4 * jq + 0][c] = v.x;
            st[4 * jq + 1][c] = v.y;
            st[4 * jq + 2][c] = v.z;
            st[4 * jq + 3][c] = v.w;
        }
        __syncthreads();
        if (t < 64) {                          // fp32 interleaved coords
            f32x4 v = { st[t][0], st[t][1], st[t][2], 0.f };
            *(f32x4*)(xyz3 + ((size_t)(b * N_ + j0 + t)) * 4) = v;
        }
        // pack: 8 x uint4 per record (64 feature shorts)
        uint4_t* outp4 = (uint4_t*)(ft + (size_t)(b * N_ + j0) * FSTR);
        for (int idx = t; idx < 64 * 8; idx += 256) {
            const int j2 = idx >> 3, q = idx & 7;
            const int cb = 3 + q * 8;          // feats channel base in st
            unsigned u[4];
#pragma unroll
            for (int e = 0; e < 4; e++) {
                const int c0 = cb + 2 * e;     // max 65, c0+1 max 66 < 67
                u[e] = (unsigned)f2b(st[j2][c0]) | ((unsigned)f2b(st[j2][c0 + 1]) << 16);
            }
            uint4_t uu = { u[0], u[1], u[2], u[3] };
            outp4[idx] = uu;
        }
    } else if (bid < 1152) {
        const int o = bid - 1024;              // 128 out-channel rows
        const float* src = lin_w + (size_t)o * (16 * CF_);
        short*       dst = lwb   + (size_t)o * AGGP_;
        for (int i = t; i < AGGP_; i += 256) {
            const int w = i / 68, c = i % 68;
            const int sc = (c < 64) ? (3 + c) : (c - 64);  // permuted column
            dst[i] = (c < CF_) ? (short)f2b(src[w * CF_ + sc]) : (short)0;
        }
    } else {
        // dxyz: one thread per (b,n,k); knn read coalesced, store coalesced
        const int i0 = (bid - 1152) * 256 + t;     // [0, 1048576)
        const int b  = i0 >> 18;                   // N*K = 262144
        const int rm = i0 & 262143;
        const int n  = rm >> 4;
        const int j  = knn[(size_t)i0];            // [B][N][K] contiguous
        const float* xb = xyz + (size_t)b * 3 * N_;
        half4 d;
        d.x = (_Float16)(xb[j]          - xb[n]);
        d.y = (_Float16)(xb[N_ + j]     - xb[N_ + n]);
        d.z = (_Float16)(xb[2 * N_ + j] - xb[2 * N_ + n]);
        d.w = (_Float16)0.f;
        *(half4*)(dxyz + (size_t)i0 * 4) = d;
    }
}

// ------------------------- pc_main phase helpers ---------------------------
// 16 threads/point: thread (p, s) reads the s-th uint2 (8 B) of each record.
__device__ __forceinline__ void gather_ft(const unsigned short* ftb, const int* ip,
                                          int s, uint2_t* fb)
{
#pragma unroll
    for (int k = 0; k < K_; k++) {
        const unsigned short* rec = ftb + (size_t)ip[k] * FSTR;
        fb[k] = *(const uint2_t*)(rec + 4 * s);   // 16 s-lanes = 2 full lines
    }
}

// thread (p, k): full MLP, all 16 w-outputs
__device__ __forceinline__ void mlp_store(
    short* wd, float d0, float d1, float d2,
    const float* w1, const float* b1, const float* w2, const float* b2)
{
    float hh[8];
#pragma unroll
    for (int i = 0; i < 8; i++)
        hh[i] = leaky(b1[i] + w1[i*3+0]*d0 + w1[i*3+1]*d1 + w1[i*3+2]*d2);
#pragma unroll
    for (int w = 0; w < 16; w++) {
        float a = b2[w];
#pragma unroll
        for (int i = 0; i < 8; i++) a += w2[w*8+i] * hh[i];
        wd[w * 16] = (short)f2b(leaky(a));
    }
}

// FT[c][k] LDS swizzle v2 (validated round 5: conflicts 5.37M->2.23M):
//   row = c ^ (s&3),  k-half hf = ((s>>2)&1)<<3 (q0 at hf, q1 at 8-hf)
// Rows 0..63 = gathered features; rows 64..66 = neighbor xyz (phase-1 regs,
// identity layout); row 67 = zero.
__device__ __forceinline__ void transpose_store(
    short* frow, const uint2_t* fb, int s)
{
    const int hf = ((s >> 2) & 1) << 3;
#pragma unroll
    for (int i = 0; i < 4; i++) {            // rows c = 4s+i, k-contiguous
        const unsigned sel = (i & 1) ? 0x07060302u : 0x05040100u;
        unsigned pk[8];
#pragma unroll
        for (int d = 0; d < 8; d++) {
            const unsigned lo = (i < 2) ? fb[2*d].x   : fb[2*d].y;
            const unsigned hi = (i < 2) ? fb[2*d+1].x : fb[2*d+1].y;
            pk[d] = __builtin_amdgcn_perm(hi, lo, sel);
        }
        const int c   = 4 * s + i;
        const int row = c ^ (s & 3);
        uint4_t q0 = { pk[0], pk[1], pk[2], pk[3] };   // logical k = 0..7
        uint4_t q1 = { pk[4], pk[5], pk[6], pk[7] };   // logical k = 8..15
        *(uint4_t*)(frow + row * 16 + hf)       = q0;
        *(uint4_t*)(frow + row * 16 + (8 - hf)) = q1;
    }
    if (s == 3) {                            // row 67 = zero (agg[w][67]=0)
        uint4_t z = {0u, 0u, 0u, 0u};
        *(uint4_t*)(frow + 67 * 16)     = z;
        *(uint4_t*)(frow + 67 * 16 + 8) = z;
    }
}

// Pair MFMA agg for the wave's points of this pass (two pair-calls).
__device__ __forceinline__ void agg_mfma(short* s_aggp, const short* s_WTp,
                                         int t, int pbase)
{
    const int lane = t & 63;
    const int wq   = lane >> 4;          // quad
    const int pr   = lane & 15;
    const int pbl  = (t >> 6) * 4;       // wave's first local point (4 waves x 4)
    const int kh   = (wq & 1) * 8;
    const int side = (wq < 2) ? 0 : 1;   // B-operand / D-row point select
    const int asid = (pr < 8) ? 0 : 1;   // A-operand point select
    const bool act = (side == asid);
    const int cq   = 4 * (wq & 1);
    const int c0   = pr & 7;
    const int bb   = c0 >> 2;
#pragma unroll
    for (int pair = 0; pair < 2; pair++) {
        const int lpA = pbl + 2 * pair;          // local (pass) point
        const int ppA = pbase + lpA;             // global (block) point
        const short8 bfr = *(const short8*)(s_WTp + (lpA + side) * WTS + pr * 16 + kh);
        const short* ap  = s_aggp + (size_t)(ppA + asid) * ASTR;
        f32x4 D[9];
#pragma unroll
        for (int cc = 0; cc < 9; cc++) {
            const int row  = (c0 + 8 * cc) ^ ((bb + 2 * cc) & 3);
            const int khcc = kh ^ (((cc >> 1) & 1) << 3);
            short8 af = {0,0,0,0,0,0,0,0};
            // cc=8 reads rows 64..67 only; active lanes have c0<4 -> bb=0,
            // key 0, bit4(c)=0: identity (matches phase-1 xyz + zero writes).
            if (act && (cc < 8 || c0 < 4))
                af = *(const short8*)(ap + row * 16 + khcc);
            D[cc] = __builtin_amdgcn_mfma_f32_16x16x32_bf16(
                        af, bfr, (f32x4){0.f,0.f,0.f,0.f}, 0, 0, 0);
        }
        __asm__ __volatile__("" ::: "memory");  // all FT reads before stores
        short* arow = s_aggp + (size_t)(ppA + side) * ASTR + pr * 68;  // w=pr
#pragma unroll
        for (int cc = 0; cc < 9; cc++) {
            if (cc == 8 && cq != 0) continue;   // c=68..71 skipped
            const unsigned lo = (unsigned)f2b(D[cc].x) | ((unsigned)f2b(D[cc].y) << 16);
            const unsigned hi = (unsigned)f2b(D[cc].z) | ((unsigned)f2b(D[cc].w) << 16);
            uint2_t pk2 = { lo, hi };
            *(uint2_t*)(arow + 8 * cc + cq) = pk2;
        }
    }
}

// ---------------------------------------------------------------------------
// Kernel 2.  Round-16: round-15 structure (best: pc_main 100.8us, XCD swizzle
// kept — FETCH 35.7->13.9 MB) + dxyz-precomputed MLP inputs.  R15 evidence:
// converting ft gathers to L2-hits didn't move time -> those latencies were
// off the critical path.  Remaining levers: x3[ja/jb] neighbor gathers are
// the last removable scatter (128 of ~400 lines/wave, -32% requests) AND the
// MLP's chain-head dependency (knn->x3 before 500-instr VALU can start).
// dxyz [B][N][K][4] fp16 makes the MLP input ONE coalesced 8-B load.  qa for
// FT rows 64..66 reconstructs as dx+ca (ca coalesced; fp16 err 5e-4 << bf16
// feature quant).  Gate: pc_main >= 97us -> front-end exhausted, declare.
// LDS 80896 B -> 2 blocks/CU; __launch_bounds__(256,2).
// ---------------------------------------------------------------------------
__global__ __launch_bounds__(256, 2) void pc_main(
    const float*          __restrict__ x3,     // [B][N][4] fp32 interleaved
    const _Float16*       __restrict__ dxyz,   // [B][N][K][4] fp16 dx
    const unsigned short* __restrict__ ft,
    const int*            __restrict__ knn,
    const float* __restrict__ w1, const float* __restrict__ b1,
    const float* __restrict__ w2, const float* __restrict__ b2,
    const short* __restrict__ lwb, const float* __restrict__ lin_b,
    float* __restrict__ out)
{
    __shared__ __align__(16) short s_agg[P_ * ASTR];   // 32 pts: FT[c][k] then agg
    __shared__ __align__(16) short s_WT[PH_ * WTS];    // per-pass [p][w*16+k]
    __shared__ int s_idx[2 * PH_ * K_];                // both passes

    const int t   = threadIdx.x;
    // XCD digit-swap (validated round 15: FETCH 35.7->13.9 MB)
    const int swz = ((blockIdx.x & 7) << 8) | (blockIdx.x >> 3);   // [0,2048)
    const int b   = swz >> 9;
    const int n0  = (swz & 511) << 5;      // 32 points per block
    const unsigned short* ftb = ft + (size_t)b * N_ * FSTR;
    const f32x4* x3b = (const f32x4*)x3 + (size_t)b * N_;

    const int p = t >> 4, s = t & 15;      // dual role: s = k in MLP, s in 2a

    // ---- front-load ALL global memory for both passes ---------------------
    const int n_a = n0 + p, n_b = n0 + PH_ + p;
    const int ja = knn[((size_t)(b * N_ + n_a)) * K_ + s];
    const int jb = knn[((size_t)(b * N_ + n_b)) * K_ + s];
    s_idx[(0 * PH_ + p) * K_ + s] = ja;
    s_idx[(1 * PH_ + p) * K_ + s] = jb;
    // MLP inputs: coalesced fp16 loads, independent of knn (chain head cut)
    const half4 hA = *(const half4*)(dxyz + ((size_t)((b * N_ + n_a) * K_ + s)) * 4);
    const half4 hB = *(const half4*)(dxyz + ((size_t)((b * N_ + n_b) * K_ + s)) * 4);
    const f32x4 ca = x3b[n_a], cb = x3b[n_b];
    const float dxa0 = (float)hA.x, dxa1 = (float)hA.y, dxa2 = (float)hA.z;
    const float dxb0 = (float)hB.x, dxb1 = (float)hB.y, dxb2 = (float)hB.z;
    __asm__ __volatile__("" ::: "memory");   // s_idx visible (wave-local)

    const int* ipa = s_idx + (0 * PH_ + p) * K_;
    const int* ipb = s_idx + (1 * PH_ + p) * K_;
    uint2_t fbA[K_], fbB[K_];
    gather_ft(ftb, ipa, s, fbA);             // in flight through pass A
    gather_ft(ftb, ipb, s, fbB);             // in flight through pass B

    // ============================ PASS A ==================================
    {   // FT rows 64..66 = neighbor xyz, reconstructed qa = dx + center
        short* frow = s_agg + (size_t)p * ASTR;
        frow[64 * 16 + s] = (short)f2b(dxa0 + ca.x);
        frow[65 * 16 + s] = (short)f2b(dxa1 + ca.y);
        frow[66 * 16 + s] = (short)f2b(dxa2 + ca.z);
    }
    mlp_store(s_WT + p * WTS + s, dxa0, dxa1, dxa2, w1, b1, w2, b2);
    __asm__ __volatile__("" ::: "memory");   // wave-local: DS pipe in-order
    transpose_store(s_agg + (size_t)p * ASTR, fbA, s);
    __asm__ __volatile__("" ::: "memory");
    agg_mfma(s_agg, s_WT, t, 0);
    __asm__ __volatile__("" ::: "memory");

    // ============================ PASS B ==================================
    {
        short* frow = s_agg + (size_t)(PH_ + p) * ASTR;
        frow[64 * 16 + s] = (short)f2b(dxb0 + cb.x);
        frow[65 * 16 + s] = (short)f2b(dxb1 + cb.y);
        frow[66 * 16 + s] = (short)f2b(dxb2 + cb.z);
    }
    mlp_store(s_WT + p * WTS + s, dxb0, dxb1, dxb2, w1, b1, w2, b2);
    __asm__ __volatile__("" ::: "memory");
    transpose_store(s_agg + (size_t)(PH_ + p) * ASTR, fbB, s);
    __asm__ __volatile__("" ::: "memory");
    agg_mfma(s_agg, s_WT, t, PH_);

    // ---------------- phase 3: out[128 x 32] = L[128x1088] @ aggT^T --------
    {
        const int lane = t & 63, wid = t >> 6;
        const int quad = lane >> 4, pr = lane & 15;
        const int kq = quad * 8;
        // A fragment: lane holds A[m=pr][k=quad*8+j]; A row = out channel
        const short* a0p = lwb + (size_t)(wid * 32 + pr) * AGGP_ + kq;
        const short* a1p = a0p + 16 * AGGP_;

        // A prologue BEFORE the barrier: lwb loads are independent of s_agg
        short8 pa0[6], pa1[6];
#pragma unroll
        for (int d = 0; d < 6; d++) {
            pa0[d] = *(const short8*)(a0p + 32 * d);
            pa1[d] = *(const short8*)(a1p + 32 * d);
        }
        __syncthreads();   // agg complete for all 32 points

        // B fragments: two point-tiles share every A load (4 MFMA / A-pair)
        const short* bp0 = s_agg + (size_t)pr * ASTR + kq;          // pts 0..15
        const short* bp1 = s_agg + (size_t)(16 + pr) * ASTR + kq;   // pts 16..31
        f32x4 acc00 = {0.f, 0.f, 0.f, 0.f};   // a0 x b0
        f32x4 acc01 = {0.f, 0.f, 0.f, 0.f};   // a0 x b1
        f32x4 acc10 = {0.f, 0.f, 0.f, 0.f};   // a1 x b0
        f32x4 acc11 = {0.f, 0.f, 0.f, 0.f};   // a1 x b1

#pragma unroll
        for (int ks = 0; ks < 34; ks++) {
            const int d = ks % 6;                      // static under full unroll
            const short8 a0c = pa0[d], a1c = pa1[d];
            if (ks + 6 < 34) {
                pa0[d] = *(const short8*)(a0p + 32 * (ks + 6));
                pa1[d] = *(const short8*)(a1p + 32 * (ks + 6));
            }
            const short8 b0 = *(const short8*)(bp0 + 32 * ks);
            const short8 b1 = *(const short8*)(bp1 + 32 * ks);
            acc00 = __builtin_amdgcn_mfma_f32_16x16x32_bf16(a0c, b0, acc00, 0, 0, 0);
            acc01 = __builtin_amdgcn_mfma_f32_16x16x32_bf16(a0c, b1, acc01, 0, 0, 0);
            acc10 = __builtin_amdgcn_mfma_f32_16x16x32_bf16(a1c, b0, acc10, 0, 0, 0);
            acc11 = __builtin_amdgcn_mfma_f32_16x16x32_bf16(a1c, b1, acc11, 0, 0, 0);
        }
        // epilogue: D row = quad*4 + r (out channel within tile), D col = pr
        const int o0 = wid * 32 + quad * 4;
#pragma unroll
        for (int r = 0; r < 4; r++) {
            const int oA = o0 + r;
            const int oB = oA + 16;
            const float bA = lin_b[oA], bB = lin_b[oB];
            float* rowA = out + ((size_t)(b * COUT_ + oA)) * N_ + n0;
            float* rowB = out + ((size_t)(b * COUT_ + oB)) * N_ + n0;
            rowA[pr]      = leaky(acc00[r] + bA);
            rowA[16 + pr] = leaky(acc01[r] + bA);
            rowB[pr]      = leaky(acc10[r] + bB);
            rowB[16 + pr] = leaky(acc11[r] + bB);
        }
    }
}

extern "C" void kernel_launch(void* const* d_in, const int* in_sizes, int n_in,
                              void* d_out, int out_size, void* d_ws, size_t ws_size,
                              hipStream_t stream)
{
    const float* xyz   = (const float*)d_in[0];
    const float* feats = (const float*)d_in[1];
    const int*   knn   = (const int*)d_in[2];
    const float* w1    = (const float*)d_in[3];
    const float* b1    = (const float*)d_in[4];
    const float* w2    = (const float*)d_in[5];
    const float* b2    = (const float*)d_in[6];
    const float* lin_w = (const float*)d_in[7];
    const float* lin_b = (const float*)d_in[8];
    float* out = (float*)d_out;

    const size_t ftBytes   = (size_t)B_ * N_ * FSTR * sizeof(short);       // 8.39 MB
    const size_t lwbBytes  = (size_t)COUT_ * AGGP_ * sizeof(short);        // 278 KB
    const size_t xyz3Bytes = (size_t)B_ * N_ * 4 * sizeof(float);          // 1 MB
    unsigned short* ft   = (unsigned short*)d_ws;
    short*          lwb  = (short*)((char*)d_ws + ftBytes);
    float*          xyz3 = (float*)((char*)d_ws + ftBytes + lwbBytes);
    _Float16*       dxyz = (_Float16*)((char*)d_ws + ftBytes + lwbBytes + xyz3Bytes);
                                                   // [B][N][K][4] fp16 = 8.39 MB

    hipLaunchKernelGGL(pc_prep, dim3(1024 + COUT_ + 4096), dim3(256), 0, stream,
                       xyz, feats, lin_w, knn, ft, lwb, xyz3, dxyz);
    hipLaunchKernelGGL(pc_main, dim3(B_ * (N_ / P_)), dim3(256), 0, stream,
                       xyz3, dxyz, ft, knn, w1, b1, w2, b2, lwb, lin_b, out);
}

// Round 17
// 181.112 us; speedup vs baseline: 1.0514x; 1.0514x over previous
//
#include <hip/hip_runtime.h>
#include <hip/hip_bf16.h>

#define B_    4
#define N_    16384
#define K_    16
#define CIN_  64
#define CF_   67          // 3 + 64 concat channels
#define COUT_ 128
#define AGGP_ 1088        // 16*68 padded flattening (c=67 slot zero per w-row)
#define P_    32          // points per block (2 passes of 16 through phases 1-2)
#define PH_   16          // points per pass
#define FSTR  64          // bf16 record stride in shorts (128 B, 2 aligned lines)
#define ASTR  1096        // agg/FT row stride in shorts (2192 B, 16B-aligned)
#define WTS   272         // s_WT point stride in shorts: [w][k] 16x16 + 16 pad
#define NEG_  0.1f

typedef __attribute__((ext_vector_type(8))) short short8;
typedef __attribute__((ext_vector_type(4))) float f32x4;
typedef __attribute__((ext_vector_type(2))) unsigned int uint2_t;
typedef __attribute__((ext_vector_type(4))) unsigned int uint4_t;

__device__ __forceinline__ unsigned short f2b(float f) {
    __hip_bfloat16 h = __float2bfloat16(f);
    return *reinterpret_cast<unsigned short*>(&h);
}
__device__ __forceinline__ float leaky(float x) { return x >= 0.f ? x : NEG_ * x; }

// ---------------------------------------------------------------------------
// Kernel 1 (fused prep):
//  blocks [0,1024):   features-only bf16 records ft [B][N][64] (128-B aligned)
//                     + interleaved fp32 xyz3 [B][N][4] (1-line coord gathers)
//  blocks [1024,1152): lin_w -> lwb bf16 [128][16*68], columns permuted to
//                     FT row order (0..63 feats, 64..66 xyz, 67 zero).
// (Round-16's dxyz precompute REVERTED: it cost ~12us of prep for -2.8us of
//  pc_main — net-negative on total.  This is the round-15 best config.)
// ---------------------------------------------------------------------------
__global__ __launch_bounds__(256) void pc_prep(
    const float* __restrict__ xyz,
    const float* __restrict__ feats,
    const float* __restrict__ lin_w,
    unsigned short* __restrict__ ft,
    short* __restrict__ lwb,
    float* __restrict__ xyz3)
{
    const int bid = blockIdx.x, t = threadIdx.x;
    if (bid < 1024) {
        __shared__ float st[64][69];           // [j_local][c], +1 pad
        const int b  = bid >> 8;
        const int j0 = (bid & 255) << 6;
        for (int ii = t; ii < 68 * 16; ii += 256) {
            const int c = ii >> 4, jq = ii & 15;
            f32x4 v = {0.f, 0.f, 0.f, 0.f};
            if (c < 3)
                v = *(const f32x4*)(xyz   + ((size_t)b * 3    + c)       * N_ + j0 + 4 * jq);
            else if (c < CF_)
                v = *(const f32x4*)(feats + ((size_t)b * CIN_ + (c - 3)) * N_ + j0 + 4 * jq);
            st[4 * jq + 0][c] = v.x;
            st[4 * jq + 1][c] = v.y;
            st[4 * jq + 2][c] = v.z;
            st[4 * jq + 3][c] = v.w;
        }
        __syncthreads();
        if (t < 64) {                          // fp32 interleaved coords
            f32x4 v = { st[t][0], st[t][1], st[t][2], 0.f };
            *(f32x4*)(xyz3 + ((size_t)(b * N_ + j0 + t)) * 4) = v;
        }
        // pack: 8 x uint4 per record (64 feature shorts)
        uint4_t* outp4 = (uint4_t*)(ft + (size_t)(b * N_ + j0) * FSTR);
        for (int idx = t; idx < 64 * 8; idx += 256) {
            const int j2 = idx >> 3, q = idx & 7;
            const int cb = 3 + q * 8;          // feats channel base in st
            unsigned u[4];
#pragma unroll
            for (int e = 0; e < 4; e++) {
                const int c0 = cb + 2 * e;     // max 65, c0+1 max 66 < 67
                u[e] = (unsigned)f2b(st[j2][c0]) | ((unsigned)f2b(st[j2][c0 + 1]) << 16);
            }
            uint4_t uu = { u[0], u[1], u[2], u[3] };
            outp4[idx] = uu;
        }
    } else {
        const int o = bid - 1024;              // 128 out-channel rows
        const float* src = lin_w + (size_t)o * (16 * CF_);
        short*       dst = lwb   + (size_t)o * AGGP_;
        for (int i = t; i < AGGP_; i += 256) {
            const int w = i / 68, c = i % 68;
            const int sc = (c < 64) ? (3 + c) : (c - 64);  // permuted column
            dst[i] = (c < CF_) ? (short)f2b(src[w * CF_ + sc]) : (short)0;
        }
    }
}

// ------------------------- pc_main phase helpers ---------------------------
// 16 threads/point: thread (p, s) reads the s-th uint2 (8 B) of each record.
__device__ __forceinline__ void gather_ft(const unsigned short* ftb, const int* ip,
                                          int s, uint2_t* fb)
{
#pragma unroll
    for (int k = 0; k < K_; k++) {
        const unsigned short* rec = ftb + (size_t)ip[k] * FSTR;
        fb[k] = *(const uint2_t*)(rec + 4 * s);   // 16 s-lanes = 2 full lines
    }
}

// thread (p, k): full MLP, all 16 w-outputs
__device__ __forceinline__ void mlp_store(
    short* wd, float d0, float d1, float d2,
    const float* w1, const float* b1, const float* w2, const float* b2)
{
    float hh[8];
#pragma unroll
    for (int i = 0; i < 8; i++)
        hh[i] = leaky(b1[i] + w1[i*3+0]*d0 + w1[i*3+1]*d1 + w1[i*3+2]*d2);
#pragma unroll
    for (int w = 0; w < 16; w++) {
        float a = b2[w];
#pragma unroll
        for (int i = 0; i < 8; i++) a += w2[w*8+i] * hh[i];
        wd[w * 16] = (short)f2b(leaky(a));
    }
}

// FT[c][k] LDS swizzle v2 (validated round 5: conflicts 5.37M->2.23M):
//   row = c ^ (s&3),  k-half hf = ((s>>2)&1)<<3 (q0 at hf, q1 at 8-hf)
// Rows 0..63 = gathered features; rows 64..66 = neighbor xyz (phase-1 regs,
// identity layout); row 67 = zero.
__device__ __forceinline__ void transpose_store(
    short* frow, const uint2_t* fb, int s)
{
    const int hf = ((s >> 2) & 1) << 3;
#pragma unroll
    for (int i = 0; i < 4; i++) {            // rows c = 4s+i, k-contiguous
        const unsigned sel = (i & 1) ? 0x07060302u : 0x05040100u;
        unsigned pk[8];
#pragma unroll
        for (int d = 0; d < 8; d++) {
            const unsigned lo = (i < 2) ? fb[2*d].x   : fb[2*d].y;
            const unsigned hi = (i < 2) ? fb[2*d+1].x : fb[2*d+1].y;
            pk[d] = __builtin_amdgcn_perm(hi, lo, sel);
        }
        const int c   = 4 * s + i;
        const int row = c ^ (s & 3);
        uint4_t q0 = { pk[0], pk[1], pk[2], pk[3] };   // logical k = 0..7
        uint4_t q1 = { pk[4], pk[5], pk[6], pk[7] };   // logical k = 8..15
        *(uint4_t*)(frow + row * 16 + hf)       = q0;
        *(uint4_t*)(frow + row * 16 + (8 - hf)) = q1;
    }
    if (s == 3) {                            // row 67 = zero (agg[w][67]=0)
        uint4_t z = {0u, 0u, 0u, 0u};
        *(uint4_t*)(frow + 67 * 16)     = z;
        *(uint4_t*)(frow + 67 * 16 + 8) = z;
    }
}

// Pair MFMA agg for the wave's points of this pass (two pair-calls).
__device__ __forceinline__ void agg_mfma(short* s_aggp, const short* s_WTp,
                                         int t, int pbase)
{
    const int lane = t & 63;
    const int wq   = lane >> 4;          // quad
    const int pr   = lane & 15;
    const int pbl  = (t >> 6) * 4;       // wave's first local point (4 waves x 4)
    const int kh   = (wq & 1) * 8;
    const int side = (wq < 2) ? 0 : 1;   // B-operand / D-row point select
    const int asid = (pr < 8) ? 0 : 1;   // A-operand point select
    const bool act = (side == asid);
    const int cq   = 4 * (wq & 1);
    const int c0   = pr & 7;
    const int bb   = c0 >> 2;
#pragma unroll
    for (int pair = 0; pair < 2; pair++) {
        const int lpA = pbl + 2 * pair;          // local (pass) point
        const int ppA = pbase + lpA;             // global (block) point
        const short8 bfr = *(const short8*)(s_WTp + (lpA + side) * WTS + pr * 16 + kh);
        const short* ap  = s_aggp + (size_t)(ppA + asid) * ASTR;
        f32x4 D[9];
#pragma unroll
        for (int cc = 0; cc < 9; cc++) {
            const int row  = (c0 + 8 * cc) ^ ((bb + 2 * cc) & 3);
            const int khcc = kh ^ (((cc >> 1) & 1) << 3);
            short8 af = {0,0,0,0,0,0,0,0};
            // cc=8 reads rows 64..67 only; active lanes have c0<4 -> bb=0,
            // key 0, bit4(c)=0: identity (matches phase-1 xyz + zero writes).
            if (act && (cc < 8 || c0 < 4))
                af = *(const short8*)(ap + row * 16 + khcc);
            D[cc] = __builtin_amdgcn_mfma_f32_16x16x32_bf16(
                        af, bfr, (f32x4){0.f,0.f,0.f,0.f}, 0, 0, 0);
        }
        __asm__ __volatile__("" ::: "memory");  // all FT reads before stores
        short* arow = s_aggp + (size_t)(ppA + side) * ASTR + pr * 68;  // w=pr
#pragma unroll
        for (int cc = 0; cc < 9; cc++) {
            if (cc == 8 && cq != 0) continue;   // c=68..71 skipped
            const unsigned lo = (unsigned)f2b(D[cc].x) | ((unsigned)f2b(D[cc].y) << 16);
            const unsigned hi = (unsigned)f2b(D[cc].z) | ((unsigned)f2b(D[cc].w) << 16);
            uint2_t pk2 = { lo, hi };
            *(uint2_t*)(arow + 8 * cc + cq) = pk2;
        }
    }
}

// ---------------------------------------------------------------------------
// Kernel 2.  FINAL (round-15 config, best measured: total 181.1us, pc_main
// 100.8us).  Session ledger of measurement-closed levers: scheduling (r3/r4:
// compiler fixed-point, forcing regresses), LDS conflicts (r5: 9.57M->2.23M),
// P=32 amortization (r6; r14 P=16 worse), front-load serial chain (r8: -23us),
// 128-B record format (r9: -23us), occupancy box all corners (r11-14: round-9
// 2blk x 256thr optimum), XCD swizzle (r15: FETCH 35.7->13.9 MB), gather
// removal (r16: +2.8% only, net-negative with prep cost -> reverted).
// Remaining stall is gather-dependent latency at the LDS-pinned occupancy
// optimum; no lever with EV > noise remains in this structure family.
// LDS 80896 B -> 2 blocks/CU; __launch_bounds__(256,2); VGPR 108.
// ---------------------------------------------------------------------------
__global__ __launch_bounds__(256, 2) void pc_main(
    const float*          __restrict__ x3,     // [B][N][4] fp32 interleaved
    const unsigned short* __restrict__ ft,
    const int*            __restrict__ knn,
    const float* __restrict__ w1, const float* __restrict__ b1,
    const float* __restrict__ w2, const float* __restrict__ b2,
    const short* __restrict__ lwb, const float* __restrict__ lin_b,
    float* __restrict__ out)
{
    __shared__ __align__(16) short s_agg[P_ * ASTR];   // 32 pts: FT[c][k] then agg
    __shared__ __align__(16) short s_WT[PH_ * WTS];    // per-pass [p][w*16+k]
    __shared__ int s_idx[2 * PH_ * K_];                // both passes

    const int t   = threadIdx.x;
    // XCD digit-swap (validated round 15: FETCH 35.7->13.9 MB)
    const int swz = ((blockIdx.x & 7) << 8) | (blockIdx.x >> 3);   // [0,2048)
    const int b   = swz >> 9;
    const int n0  = (swz & 511) << 5;      // 32 points per block
    const unsigned short* ftb = ft + (size_t)b * N_ * FSTR;
    const f32x4* x3b = (const f32x4*)x3 + (size_t)b * N_;

    const int p = t >> 4, s = t & 15;      // dual role: s = k in MLP, s in 2a

    // ---- front-load ALL global memory for both passes ---------------------
    const int n_a = n0 + p, n_b = n0 + PH_ + p;
    const int ja = knn[((size_t)(b * N_ + n_a)) * K_ + s];
    const int jb = knn[((size_t)(b * N_ + n_b)) * K_ + s];
    s_idx[(0 * PH_ + p) * K_ + s] = ja;
    s_idx[(1 * PH_ + p) * K_ + s] = jb;
    const f32x4 qa = x3b[ja], qb = x3b[jb];
    const f32x4 ca = x3b[n_a], cb = x3b[n_b];
    const float dxa0 = qa.x - ca.x, dxa1 = qa.y - ca.y, dxa2 = qa.z - ca.z;
    const float dxb0 = qb.x - cb.x, dxb1 = qb.y - cb.y, dxb2 = qb.z - cb.z;
    __asm__ __volatile__("" ::: "memory");   // s_idx visible (wave-local)

    const int* ipa = s_idx + (0 * PH_ + p) * K_;
    const int* ipb = s_idx + (1 * PH_ + p) * K_;
    uint2_t fbA[K_], fbB[K_];
    gather_ft(ftb, ipa, s, fbA);             // in flight through pass A
    gather_ft(ftb, ipb, s, fbB);             // in flight through pass B

    // ============================ PASS A ==================================
    {   // FT rows 64..66 = neighbor xyz, straight from registers (identity)
        short* frow = s_agg + (size_t)p * ASTR;
        frow[64 * 16 + s] = (short)f2b(qa.x);
        frow[65 * 16 + s] = (short)f2b(qa.y);
        frow[66 * 16 + s] = (short)f2b(qa.z);
    }
    mlp_store(s_WT + p * WTS + s, dxa0, dxa1, dxa2, w1, b1, w2, b2);
    __asm__ __volatile__("" ::: "memory");   // wave-local: DS pipe in-order
    transpose_store(s_agg + (size_t)p * ASTR, fbA, s);
    __asm__ __volatile__("" ::: "memory");
    agg_mfma(s_agg, s_WT, t, 0);
    __asm__ __volatile__("" ::: "memory");

    // ============================ PASS B ==================================
    {
        short* frow = s_agg + (size_t)(PH_ + p) * ASTR;
        frow[64 * 16 + s] = (short)f2b(qb.x);
        frow[65 * 16 + s] = (short)f2b(qb.y);
        frow[66 * 16 + s] = (short)f2b(qb.z);
    }
    mlp_store(s_WT + p * WTS + s, dxb0, dxb1, dxb2, w1, b1, w2, b2);
    __asm__ __volatile__("" ::: "memory");
    transpose_store(s_agg + (size_t)(PH_ + p) * ASTR, fbB, s);
    __asm__ __volatile__("" ::: "memory");
    agg_mfma(s_agg, s_WT, t, PH_);

    // ---------------- phase 3: out[128 x 32] = L[128x1088] @ aggT^T --------
    {
        const int lane = t & 63, wid = t >> 6;
        const int quad = lane >> 4, pr = lane & 15;
        const int kq = quad * 8;
        // A fragment: lane holds A[m=pr][k=quad*8+j]; A row = out channel
        const short* a0p = lwb + (size_t)(wid * 32 + pr) * AGGP_ + kq;
        const short* a1p = a0p + 16 * AGGP_;

        // A prologue BEFORE the barrier: lwb loads are independent of s_agg
        short8 pa0[6], pa1[6];
#pragma unroll
        for (int d = 0; d < 6; d++) {
            pa0[d] = *(const short8*)(a0p + 32 * d);
            pa1[d] = *(const short8*)(a1p + 32 * d);
        }
        __syncthreads();   // agg complete for all 32 points

        // B fragments: two point-tiles share every A load (4 MFMA / A-pair)
        const short* bp0 = s_agg + (size_t)pr * ASTR + kq;          // pts 0..15
        const short* bp1 = s_agg + (size_t)(16 + pr) * ASTR + kq;   // pts 16..31
        f32x4 acc00 = {0.f, 0.f, 0.f, 0.f};   // a0 x b0
        f32x4 acc01 = {0.f, 0.f, 0.f, 0.f};   // a0 x b1
        f32x4 acc10 = {0.f, 0.f, 0.f, 0.f};   // a1 x b0
        f32x4 acc11 = {0.f, 0.f, 0.f, 0.f};   // a1 x b1

#pragma unroll
        for (int ks = 0; ks < 34; ks++) {
            const int d = ks % 6;                      // static under full unroll
            const short8 a0c = pa0[d], a1c = pa1[d];
            if (ks + 6 < 34) {
                pa0[d] = *(const short8*)(a0p + 32 * (ks + 6));
                pa1[d] = *(const short8*)(a1p + 32 * (ks + 6));
            }
            const short8 b0 = *(const short8*)(bp0 + 32 * ks);
            const short8 b1 = *(const short8*)(bp1 + 32 * ks);
            acc00 = __builtin_amdgcn_mfma_f32_16x16x32_bf16(a0c, b0, acc00, 0, 0, 0);
            acc01 = __builtin_amdgcn_mfma_f32_16x16x32_bf16(a0c, b1, acc01, 0, 0, 0);
            acc10 = __builtin_amdgcn_mfma_f32_16x16x32_bf16(a1c, b0, acc10, 0, 0, 0);
            acc11 = __builtin_amdgcn_mfma_f32_16x16x32_bf16(a1c, b1, acc11, 0, 0, 0);
        }
        // epilogue: D row = quad*4 + r (out channel within tile), D col = pr
        const int o0 = wid * 32 + quad * 4;
#pragma unroll
        for (int r = 0; r < 4; r++) {
            const int oA = o0 + r;
            const int oB = oA + 16;
            const float bA = lin_b[oA], bB = lin_b[oB];
            float* rowA = out + ((size_t)(b * COUT_ + oA)) * N_ + n0;
            float* rowB = out + ((size_t)(b * COUT_ + oB)) * N_ + n0;
            rowA[pr]      = leaky(acc00[r] + bA);
            rowA[16 + pr] = leaky(acc01[r] + bA);
            rowB[pr]      = leaky(acc10[r] + bB);
            rowB[16 + pr] = leaky(acc11[r] + bB);
        }
    }
}

extern "C" void kernel_launch(void* const* d_in, const int* in_sizes, int n_in,
                              void* d_out, int out_size, void* d_ws, size_t ws_size,
                              hipStream_t stream)
{
    const float* xyz   = (const float*)d_in[0];
    const float* feats = (const float*)d_in[1];
    const int*   knn   = (const int*)d_in[2];
    const float* w1    = (const float*)d_in[3];
    const float* b1    = (const float*)d_in[4];
    const float* w2    = (const float*)d_in[5];
    const float* b2    = (const float*)d_in[6];
    const float* lin_w = (const float*)d_in[7];
    const float* lin_b = (const float*)d_in[8];
    float* out = (float*)d_out;

    const size_t ftBytes  = (size_t)B_ * N_ * FSTR * sizeof(short);   // 8.39 MB
    const size_t lwbBytes = (size_t)COUT_ * AGGP_ * sizeof(short);    // 278 KB
    unsigned short* ft   = (unsigned short*)d_ws;
    short*          lwb  = (short*)((char*)d_ws + ftBytes);
    float*          xyz3 = (float*)((char*)d_ws + ftBytes + lwbBytes); // 1 MB

    hipLaunchKernelGGL(pc_prep, dim3(1024 + COUT_), dim3(256), 0, stream,
                       xyz, feats, lin_w, ft, lwb, xyz3);
    hipLaunchKernelGGL(pc_main, dim3(B_ * (N_ / P_)), dim3(256), 0, stream,
                       xyz3, ft, knn, w1, b1, w2, b2, lwb, lin_b, out);
}